// Round 11
// baseline (236.235 us; speedup 1.0000x reference)
//
#include <hip/hip_runtime.h>
#include <hip/hip_bf16.h>

#define BQ 8
#define TT 1024
#define CC 768
#define NH 12
#define HD 64
#define BH (BQ*NH)      // 96
#define MROWS (BQ*TT)   // 8192
#define NQKV (3*CC)     // 2304
#define KD CC           // 768

typedef unsigned short u16;
typedef __attribute__((ext_vector_type(4))) short short4v;
typedef __attribute__((ext_vector_type(8))) short short8v;
typedef __attribute__((ext_vector_type(4))) float floatx4;
typedef __attribute__((address_space(1))) const unsigned int gu32;
typedef __attribute__((address_space(3))) unsigned int lu32;

__device__ __forceinline__ float bf2f(u16 u) {
  union { unsigned int i; float f; } c; c.i = ((unsigned int)u) << 16; return c.f;
}
__device__ __forceinline__ u16 f2bf(float f) {
  union { __hip_bfloat16 h; u16 u; } c;
  c.h = __float2bfloat16(f);
  return c.u;
}
__device__ __forceinline__ float fast_exp2(float x) {
  return __builtin_amdgcn_exp2f(x);   // v_exp_f32 (base-2)
}
// async global->LDS, 16 B per lane; LDS dest = wave-uniform base + lane*16
__device__ __forceinline__ void async_ld16(const u16* g, u16* l) {
  __builtin_amdgcn_global_load_lds((gu32*)g, (lu32*)l, 16, 0, 0);
}

// ---------------- fused prep: x->bf16 convert + 2 weight transposes + mv zero ----------------
#define PREP_CONV 6144
#define PREP_WA   1728
#define PREP_WP   576
#define PREP_TOTAL (PREP_CONV + PREP_WA + PREP_WP)   // 8448; +1 zero block

__global__ __launch_bounds__(256) void prep_kernel(
    const float* __restrict__ x, u16* __restrict__ xb,
    const float* __restrict__ Wattn, u16* __restrict__ WtA,
    const float* __restrict__ Wproj, u16* __restrict__ WtP,
    float* __restrict__ mvz)
{
  __shared__ float tile[32][33];
  int bid = blockIdx.x;
  int tid = threadIdx.x;
  if (bid == PREP_TOTAL) {   // zero vmean accumulator
    for (int i = tid; i < BH * HD; i += 256) mvz[i] = 0.f;
    return;
  }
  if (bid < PREP_CONV) {
    int i = (bid * 256 + tid) * 4;
    floatx4 v = *(const floatx4*)(x + i);
    short4v o;
    o[0] = (short)f2bf(v[0]); o[1] = (short)f2bf(v[1]);
    o[2] = (short)f2bf(v[2]); o[3] = (short)f2bf(v[3]);
    *(short4v*)(xb + i) = o;
    return;
  }
  const float* in; u16* out; int R, Cc, b2;
  if (bid < PREP_CONV + PREP_WA) { in = Wattn; out = WtA; R = KD; Cc = NQKV; b2 = bid - PREP_CONV; }
  else                           { in = Wproj; out = WtP; R = CC; Cc = CC;   b2 = bid - PREP_CONV - PREP_WA; }
  int ct = Cc >> 5;
  int bx = b2 % ct;
  int by = b2 / ct;
  int tx = tid & 31;
  int ty = tid >> 5;    // 0..7
  int c0 = bx << 5, r0 = by << 5;
#pragma unroll
  for (int s = 0; s < 4; ++s)
    tile[ty + s*8][tx] = in[(size_t)(r0 + ty + s*8) * Cc + c0 + tx];
  __syncthreads();
#pragma unroll
  for (int s = 0; s < 4; ++s)
    out[(size_t)(c0 + ty + s*8) * R + r0 + tx] = f2bf(tile[tx][ty + s*8]);
}

// ------- GEMM: 64x128 tile, BK=64, global_load_lds + XOR bank swizzle -------
// mode 0: q/k scattered directly; V written TRANSPOSED to vtb [bh][d][t] via
//         LDS staging; vmean partials from f32 accs. mode 1: f32 row-major out.
__global__ __launch_bounds__(256) void gemm_bt(
    const u16* __restrict__ A, const u16* __restrict__ Bt,
    const float* __restrict__ bias,
    float* __restrict__ out,
    u16* __restrict__ qo, u16* __restrict__ ko, u16* __restrict__ vo,
    float* __restrict__ mvp,
    int M, int N, int mode)
{
  __shared__ u16 smem[64 * 64 + 128 * 64];   // As | Bs ; reused as V-staging (needs 128*72)
  u16* Asm = smem;
  u16* Bsm = smem + 64 * 64;

  int tid = threadIdx.x;
  int lane = tid & 63;
  int w = tid >> 6;
  int c = lane & 15;     // fragment col
  int q4 = lane >> 4;    // quad

  int mtiles = M >> 6;
  int mt = blockIdx.x % mtiles;
  int nt = blockIdx.x / mtiles;
  int m0 = mt << 6, n0 = nt << 7;

  int wr = (w >> 1) << 5;   // 0 / 32
  int wc = (w & 1) << 6;    // 0 / 64

  int srow8 = lane >> 3;                      // 0..7
  int ug = ((lane & 7) ^ srow8) << 3;         // swizzled global k-offset (shorts)
  const u16* ag = A  + (size_t)(m0 + w * 16 + srow8) * KD + ug;
  const u16* bg = Bt + (size_t)(n0 + w * 32 + srow8) * KD + ug;
  u16* asl = &Asm[(w * 16) * 64];
  u16* bsl = &Bsm[(w * 32) * 64];

  floatx4 acc[2][4];
#pragma unroll
  for (int mi = 0; mi < 2; ++mi)
#pragma unroll
    for (int ni = 0; ni < 4; ++ni) acc[mi][ni] = (floatx4){0.f, 0.f, 0.f, 0.f};

  int c7 = c & 7;

#pragma unroll 1
  for (int kt = 0; kt < KD; kt += 64) {
    async_ld16(ag + kt,              asl);
    async_ld16(ag + kt + 8 * KD,     asl + 8 * 64);
    async_ld16(bg + kt,              bsl);
    async_ld16(bg + kt + 8 * KD,     bsl + 8 * 64);
    async_ld16(bg + kt + 16 * KD,    bsl + 16 * 64);
    async_ld16(bg + kt + 24 * KD,    bsl + 24 * 64);
    __syncthreads();

    short8v af[2][2], bf[4][2];
#pragma unroll
    for (int kc = 0; kc < 2; ++kc) {
      int uoff = ((kc * 4 + q4) ^ c7) << 3;
#pragma unroll
      for (int mi = 0; mi < 2; ++mi)
        af[mi][kc] = *(const short8v*)&Asm[(wr + mi * 16 + c) * 64 + uoff];
#pragma unroll
      for (int ni = 0; ni < 4; ++ni)
        bf[ni][kc] = *(const short8v*)&Bsm[(wc + ni * 16 + c) * 64 + uoff];
    }
#pragma unroll
    for (int kc = 0; kc < 2; ++kc)
#pragma unroll
      for (int mi = 0; mi < 2; ++mi)
#pragma unroll
        for (int ni = 0; ni < 4; ++ni)
          acc[mi][ni] = __builtin_amdgcn_mfma_f32_16x16x32_bf16(af[mi][kc], bf[ni][kc], acc[mi][ni], 0, 0, 0);
    __syncthreads();
  }

  if (mode == 0) {
    int which = (n0 + wc) / CC;          // per-wave (128-blocks can straddle q/k and k/v)
    int nbase = (n0 + wc) - which * CC;
    int bb = m0 >> 10;                   // m-range (64) never straddles a batch
    int t0 = m0 & 1023;

    if (which < 2) {
      // direct scatter: 16 c-lanes cover a contiguous 32B segment -> coalesces
      u16* dst0 = (which == 0) ? qo : ko;
#pragma unroll
      for (int ni = 0; ni < 4; ++ni) {
        int nn = nbase + ni * 16 + c;
        int hh = nn >> 6, dd = nn & 63;
        float bv = bias[which * CC + nn];
#pragma unroll
        for (int mi = 0; mi < 2; ++mi) {
#pragma unroll
          for (int r = 0; r < 4; ++r) {
            int tt2 = t0 + wr + mi * 16 + q4 * 4 + r;
            dst0[(((size_t)(bb * NH + hh)) * TT + tt2) * HD + dd] = f2bf(acc[mi][ni][r] + bv);
          }
        }
      }
    }
    // V path: block-uniform wrapper (n0 is uniform) -> barrier is legal
    if (n0 + 127 >= 2 * CC) {
      u16* Ct = smem;                    // [128 n][64 t] stride 72 (18432B <= 24576)
      if (which == 2) {
#pragma unroll
        for (int ni = 0; ni < 4; ++ni) {
          float bv = bias[2 * CC + nbase + ni * 16 + c];
#pragma unroll
          for (int mi = 0; mi < 2; ++mi) {
            short4v pk;
#pragma unroll
            for (int r = 0; r < 4; ++r) pk[r] = (short)f2bf(acc[mi][ni][r] + bv);
            *(short4v*)&Ct[(wc + ni * 16 + c) * 72 + wr + mi * 16 + q4 * 4] = pk;
          }
        }
      }
      __syncthreads();
#pragma unroll
      for (int j = 0; j < 4; ++j) {
        int flat = tid + j * 256;        // [128 rows][8 units of 16B]
        int drow = flat >> 3, u = flat & 7;
        int nn2 = n0 + drow;
        if (nn2 >= 2 * CC) {
          int nv = nn2 - 2 * CC;
          int h2 = nv >> 6, d2 = nv & 63;
          short8v val = *(const short8v*)&Ct[drow * 72 + u * 8];
          *(short8v*)&vo[(((size_t)(bb * NH + h2)) * HD + d2) * TT + t0 + u * 8] = val;
        }
      }
      // vmean partials from f32 accs (+bias): each wave sums its 32 t-rows
      if (which == 2) {
        int hw = nbase >> 6;             // wave covers exactly one head
        int bhw = bb * NH + hw;
#pragma unroll
        for (int ni = 0; ni < 4; ++ni) {
          float bv = bias[2 * CC + nbase + ni * 16 + c];
          float s = 8.0f * bv;
#pragma unroll
          for (int mi = 0; mi < 2; ++mi)
#pragma unroll
            for (int r = 0; r < 4; ++r) s += acc[mi][ni][r];
          s += __shfl_xor(s, 16);
          s += __shfl_xor(s, 32);        // sum over this wave's 32 rows
          if (q4 == 0) atomicAdd(&mvp[bhw * HD + ni * 16 + c], s);
        }
      }
    }
  } else {
#pragma unroll
    for (int ni = 0; ni < 4; ++ni) {
      int nn = n0 + wc + ni * 16 + c;
      float bv = bias[nn];
#pragma unroll
      for (int mi = 0; mi < 2; ++mi) {
#pragma unroll
        for (int r = 0; r < 4; ++r) {
          int mm = m0 + wr + mi * 16 + q4 * 4 + r;
          out[(size_t)mm * N + nn] = acc[mi][ni][r] + bv;
        }
      }
    }
  }
}

// ------- proj GEMM: 64x64 tile, BK=64, 1536 blocks -------
__global__ __launch_bounds__(256) void gemm_proj(
    const u16* __restrict__ A, const u16* __restrict__ Bt,
    const float* __restrict__ bias, float* __restrict__ out)
{
  __shared__ u16 As[64 * 64];
  __shared__ u16 Bs[64 * 64];

  int tid = threadIdx.x;
  int lane = tid & 63;
  int w = tid >> 6;
  int c = lane & 15;
  int q4 = lane >> 4;

  int mt = blockIdx.x & 127;      // 128 mtiles
  int nt = blockIdx.x >> 7;       // 12 ntiles
  int m0 = mt << 6, n0 = nt << 6;

  int wr = (w >> 1) << 5;   // 0 / 32
  int wc = (w & 1) << 5;    // 0 / 32

  int srow8 = lane >> 3;
  int ug = ((lane & 7) ^ srow8) << 3;
  const u16* ag = A  + (size_t)(m0 + w * 16 + srow8) * KD + ug;
  const u16* bg = Bt + (size_t)(n0 + w * 16 + srow8) * KD + ug;
  u16* asl = &As[(w * 16) * 64];
  u16* bsl = &Bs[(w * 16) * 64];

  floatx4 acc[2][2];
#pragma unroll
  for (int mi = 0; mi < 2; ++mi)
#pragma unroll
    for (int ni = 0; ni < 2; ++ni) acc[mi][ni] = (floatx4){0.f, 0.f, 0.f, 0.f};

  int c7 = c & 7;

#pragma unroll 1
  for (int kt = 0; kt < KD; kt += 64) {
    async_ld16(ag + kt,          asl);
    async_ld16(ag + kt + 8 * KD, asl + 8 * 64);
    async_ld16(bg + kt,          bsl);
    async_ld16(bg + kt + 8 * KD, bsl + 8 * 64);
    __syncthreads();

    short8v af[2][2], bf[2][2];
#pragma unroll
    for (int kc = 0; kc < 2; ++kc) {
      int uoff = ((kc * 4 + q4) ^ c7) << 3;
#pragma unroll
      for (int mi = 0; mi < 2; ++mi)
        af[mi][kc] = *(const short8v*)&As[(wr + mi * 16 + c) * 64 + uoff];
#pragma unroll
      for (int ni = 0; ni < 2; ++ni)
        bf[ni][kc] = *(const short8v*)&Bs[(wc + ni * 16 + c) * 64 + uoff];
    }
#pragma unroll
    for (int kc = 0; kc < 2; ++kc)
#pragma unroll
      for (int mi = 0; mi < 2; ++mi)
#pragma unroll
        for (int ni = 0; ni < 2; ++ni)
          acc[mi][ni] = __builtin_amdgcn_mfma_f32_16x16x32_bf16(af[mi][kc], bf[ni][kc], acc[mi][ni], 0, 0, 0);
    __syncthreads();
  }

#pragma unroll
  for (int ni = 0; ni < 2; ++ni) {
    int nn = n0 + wc + ni * 16 + c;
    float bv = bias[nn];
#pragma unroll
    for (int mi = 0; mi < 2; ++mi) {
#pragma unroll
      for (int r = 0; r < 4; ++r) {
        int mm = m0 + wr + mi * 16 + q4 * 4 + r;
        out[(size_t)mm * CC + nn] = acc[mi][ni][r] + bv;
      }
    }
  }
}

// ---------------- MFMA flash attention: BARRIER-FREE, L2-direct K/V ----------------
// K/V per bh = 256KB; XCD swizzle puts 12 bh per XCD = 3MB -> L2-resident.
// m169 catalog: LDS-staging L2-fit data is pure overhead. K and V^T fragments
// are read DIRECTLY from global (all 4 waves read identical addresses -> L2
// broadcast). Only Ps (wave-private P transpose buffer) stays in LDS ->
// ZERO __syncthreads in the kernel. Merged dual-q-tile (qtA=pair, qtB=15-pair)
// per block; shared kf loads feed both tiles' QK MFMAs.
#define LDW 72
#define SCL 0.18033688f   // (1/sqrt(64)) * log2(e); softmax in exp2 domain

__global__ __launch_bounds__(256, 3) void attn_kernel(
    const u16* __restrict__ qb, const u16* __restrict__ kb,
    const u16* __restrict__ vtb, const int* __restrict__ mask,
    const float* __restrict__ meanv,
    u16* __restrict__ outb)
{
  __shared__ u16 Ps[4][16 * LDW];    // per-wave P [row][key] (wave-private)

  int tid = threadIdx.x;
  int lane = tid & 63;
  int w = tid >> 6;
  int c = lane & 15;
  int q4 = lane >> 4;

  // XCD-aware bijective swizzle: nwg=768, 768%8==0 -> lbid = (hw&7)*96 + hw/8
  int lbid = ((blockIdx.x & 7) * 96) + (blockIdx.x >> 3);
  int pair = lbid & 7;
  int bh = lbid >> 3;
  int b = bh / NH;
  int h = bh - b * NH;

  int qtA = pair;          // 0..7
  int qtB = 15 - pair;     // 8..15  (qtA < qtB always)
  int rowbaseA = (qtA << 6) + (w << 4);
  int rowbaseB = (qtB << 6) + (w << 4);

  const u16* kbase = kb + (size_t)bh * TT * HD;    // [t][d]
  const u16* vbase = vtb + (size_t)bh * HD * TT;   // [d][t]
  u16* pw = &Ps[w][0];

  short8v onesv;
#pragma unroll
  for (int j = 0; j < 8; ++j) onesv[j] = (short)0x3F80;   // bf16 1.0

  short8v qfA[2], qfB[2];
  {
    const u16* qpA = qb + ((size_t)bh * TT + rowbaseA + c) * HD + q4 * 8;
    qfA[0] = *(const short8v*)qpA;
    qfA[1] = *(const short8v*)(qpA + 32);
    const u16* qpB = qb + ((size_t)bh * TT + rowbaseB + c) * HD + q4 * 8;
    qfB[0] = *(const short8v*)qpB;
    qfB[1] = *(const short8v*)(qpB + 32);
  }

  floatx4 oA[4], oB[4];
#pragma unroll
  for (int i = 0; i < 4; ++i) {
    oA[i] = (floatx4){0.f, 0.f, 0.f, 0.f};
    oB[i] = (floatx4){0.f, 0.f, 0.f, 0.f};
  }
  floatx4 o5A = (floatx4){0.f, 0.f, 0.f, 0.f};
  floatx4 o5B = (floatx4){0.f, 0.f, 0.f, 0.f};

  int qrl = (w << 4) + c;   // local q-row within 64-tile

#pragma unroll 1
  for (int kt = 0; kt <= qtB; ++kt) {
    bool doA = (kt <= qtA);
    int k0 = kt << 6;

    // V fragments for this k-tile, loaded once (shared by A and B PV)
    short8v vfr[2][4];
#pragma unroll
    for (int kc = 0; kc < 2; ++kc)
#pragma unroll
      for (int nt = 0; nt < 4; ++nt)
        vfr[kc][nt] = *(const short8v*)&vbase[(size_t)(nt * 16 + c) * TT + k0 + kc * 32 + q4 * 8];

    // QK for both tiles, shared kf loads. S^T: s[nt] = S[key=nt*16+q4*4+r][qrow=c]
    floatx4 sA[4], sB[4];
#pragma unroll
    for (int nt = 0; nt < 4; ++nt) {
      sA[nt] = (floatx4){0.f, 0.f, 0.f, 0.f};
      sB[nt] = (floatx4){0.f, 0.f, 0.f, 0.f};
    }
    __builtin_amdgcn_s_setprio(1);
#pragma unroll
    for (int kc = 0; kc < 2; ++kc) {
#pragma unroll
      for (int nt = 0; nt < 4; ++nt) {
        short8v kf = *(const short8v*)&kbase[(size_t)(k0 + nt * 16 + c) * HD + kc * 32 + q4 * 8];
        if (doA) sA[nt] = __builtin_amdgcn_mfma_f32_16x16x32_bf16(kf, qfA[kc], sA[nt], 0, 0, 0);
        sB[nt] = __builtin_amdgcn_mfma_f32_16x16x32_bf16(kf, qfB[kc], sB[nt], 0, 0, 0);
      }
    }
    __builtin_amdgcn_s_setprio(0);

    // ---- tile A: softmax -> Ps -> PV ----
    if (doA) {
#pragma unroll
      for (int nt = 0; nt < 4; ++nt) {
        short4v pk;
#pragma unroll
        for (int r = 0; r < 4; ++r) {
          float sv = sA[nt][r];
          if (kt == qtA && (nt * 16 + (q4 << 2) + r > qrl)) sv = -INFINITY;
          pk[r] = (short)f2bf(fast_exp2(sv * SCL));
        }
        *(short4v*)&pw[c * LDW + nt * 16 + (q4 << 2)] = pk;
      }
      __builtin_amdgcn_s_setprio(1);
#pragma unroll
      for (int kc = 0; kc < 2; ++kc) {
        short8v pf = *(const short8v*)&pw[c * LDW + kc * 32 + q4 * 8];
#pragma unroll
        for (int nt = 0; nt < 4; ++nt)
          oA[nt] = __builtin_amdgcn_mfma_f32_16x16x32_bf16(pf, vfr[kc][nt], oA[nt], 0, 0, 0);
        o5A = __builtin_amdgcn_mfma_f32_16x16x32_bf16(pf, onesv, o5A, 0, 0, 0);
      }
      __builtin_amdgcn_s_setprio(0);
    }

    // ---- tile B: softmax -> Ps (same-wave WAR ordering via lgkmcnt) ----
#pragma unroll
    for (int nt = 0; nt < 4; ++nt) {
      short4v pk;
#pragma unroll
      for (int r = 0; r < 4; ++r) {
        float sv = sB[nt][r];
        if (kt == qtB && (nt * 16 + (q4 << 2) + r > qrl)) sv = -INFINITY;
        pk[r] = (short)f2bf(fast_exp2(sv * SCL));
      }
      *(short4v*)&pw[c * LDW + nt * 16 + (q4 << 2)] = pk;
    }

    // ---- tile B: PV ----
    __builtin_amdgcn_s_setprio(1);
#pragma unroll
    for (int kc = 0; kc < 2; ++kc) {
      short8v pf = *(const short8v*)&pw[c * LDW + kc * 32 + q4 * 8];
#pragma unroll
      for (int nt = 0; nt < 4; ++nt)
        oB[nt] = __builtin_amdgcn_mfma_f32_16x16x32_bf16(pf, vfr[kc][nt], oB[nt], 0, 0, 0);
      o5B = __builtin_amdgcn_mfma_f32_16x16x32_bf16(pf, onesv, o5B, 0, 0, 0);
    }
    __builtin_amdgcn_s_setprio(0);
  }

  // ---- epilogue: both tiles ----
#pragma unroll
  for (int t = 0; t < 2; ++t) {
    int rowbase = t ? rowbaseB : rowbaseA;
    floatx4* o = t ? oB : oA;
    floatx4 o5 = t ? o5B : o5A;
    int qrow[4]; bool msk[4]; float inv[4];
#pragma unroll
    for (int r = 0; r < 4; ++r) {
      qrow[r] = rowbase + q4 * 4 + r;
      msk[r] = (mask[b * TT + qrow[r]] == 0);
      inv[r] = 1.f / o5[r];
    }
#pragma unroll
    for (int nt = 0; nt < 4; ++nt) {
      int d = nt * 16 + c;
      float mv = meanv[bh * HD + d] * 0.0009765625f;   // raw sum -> mean (1/1024)
#pragma unroll
      for (int r = 0; r < 4; ++r) {
        float val = msk[r] ? mv : o[nt][r] * inv[r];
        outb[((size_t)(b * TT + qrow[r])) * CC + h * HD + d] = f2bf(val);
      }
    }
  }
}

// ---------------- launcher ----------------
extern "C" void kernel_launch(void* const* d_in, const int* in_sizes, int n_in,
                              void* d_out, int out_size, void* d_ws, size_t ws_size,
                              hipStream_t stream)
{
  (void)in_sizes; (void)n_in; (void)out_size; (void)ws_size;
  const float* x     = (const float*)d_in[0];
  const int*   mask  = (const int*)d_in[1];
  const float* Wattn = (const float*)d_in[2];
  const float* battn = (const float*)d_in[3];
  const float* Wproj = (const float*)d_in[4];
  const float* bproj = (const float*)d_in[5];
  float* out = (float*)d_out;

  char* ws = (char*)d_ws;
  size_t off = 0;
  auto alloc = [&](size_t bytes) -> void* {
    void* p = ws + off;
    off += (bytes + 255) & ~(size_t)255;
    return p;
  };
  u16* WtA  = (u16*)alloc((size_t)NQKV * KD * 2);
  u16* WtP  = (u16*)alloc((size_t)CC * CC * 2);
  u16* xb   = (u16*)alloc((size_t)MROWS * CC * 2);
  u16* qbuf = (u16*)alloc((size_t)MROWS * CC * 2);
  u16* kbuf = (u16*)alloc((size_t)MROWS * CC * 2);
  u16* vtb  = (u16*)alloc((size_t)MROWS * CC * 2);   // V^T [bh][d][t] (written by gemm0)
  u16* abuf = (u16*)alloc((size_t)MROWS * CC * 2);
  float* mv = (float*)alloc((size_t)BH * HD * 4);

  prep_kernel<<<PREP_TOTAL + 1, 256, 0, stream>>>(x, xb, Wattn, WtA, Wproj, WtP, mv);

  gemm_bt<<<(MROWS/64)*(NQKV/128), 256, 0, stream>>>(
      xb, WtA, battn, nullptr, qbuf, kbuf, vtb, mv, MROWS, NQKV, 0);

  attn_kernel<<<BH * 8, 256, 0, stream>>>(qbuf, kbuf, vtb, mask, mv, abuf);

  gemm_proj<<<(MROWS/64)*(CC/64), 256, 0, stream>>>(abuf, WtP, bproj, out);
}

// Round 12
// 177.530 us; speedup vs baseline: 1.3307x; 1.3307x over previous
//
#include <hip/hip_runtime.h>
#include <hip/hip_bf16.h>

#define BQ 8
#define TT 1024
#define CC 768
#define NH 12
#define HD 64
#define BH (BQ*NH)      // 96
#define MROWS (BQ*TT)   // 8192
#define NQKV (3*CC)     // 2304
#define KD CC           // 768

typedef unsigned short u16;
typedef __attribute__((ext_vector_type(4))) short short4v;
typedef __attribute__((ext_vector_type(8))) short short8v;
typedef __attribute__((ext_vector_type(4))) float floatx4;
typedef __attribute__((address_space(1))) const unsigned int gu32;
typedef __attribute__((address_space(3))) unsigned int lu32;

__device__ __forceinline__ float bf2f(u16 u) {
  union { unsigned int i; float f; } c; c.i = ((unsigned int)u) << 16; return c.f;
}
__device__ __forceinline__ u16 f2bf(float f) {
  union { __hip_bfloat16 h; u16 u; } c;
  c.h = __float2bfloat16(f);
  return c.u;
}
__device__ __forceinline__ float fast_exp2(float x) {
  return __builtin_amdgcn_exp2f(x);   // v_exp_f32 (base-2)
}
// async global->LDS, 16 B per lane; LDS dest = wave-uniform base + lane*16
__device__ __forceinline__ void async_ld16(const u16* g, u16* l) {
  __builtin_amdgcn_global_load_lds((gu32*)g, (lu32*)l, 16, 0, 0);
}

// ---------------- fused prep: x->bf16 convert + 2 weight transposes + mv zero ----------------
#define PREP_CONV 6144
#define PREP_WA   1728
#define PREP_WP   576
#define PREP_TOTAL (PREP_CONV + PREP_WA + PREP_WP)   // 8448; +1 zero block

__global__ __launch_bounds__(256) void prep_kernel(
    const float* __restrict__ x, u16* __restrict__ xb,
    const float* __restrict__ Wattn, u16* __restrict__ WtA,
    const float* __restrict__ Wproj, u16* __restrict__ WtP,
    float* __restrict__ mvz)
{
  __shared__ float tile[32][33];
  int bid = blockIdx.x;
  int tid = threadIdx.x;
  if (bid == PREP_TOTAL) {   // zero vmean accumulator
    for (int i = tid; i < BH * HD; i += 256) mvz[i] = 0.f;
    return;
  }
  if (bid < PREP_CONV) {
    int i = (bid * 256 + tid) * 4;
    floatx4 v = *(const floatx4*)(x + i);
    short4v o;
    o[0] = (short)f2bf(v[0]); o[1] = (short)f2bf(v[1]);
    o[2] = (short)f2bf(v[2]); o[3] = (short)f2bf(v[3]);
    *(short4v*)(xb + i) = o;
    return;
  }
  const float* in; u16* out; int R, Cc, b2;
  if (bid < PREP_CONV + PREP_WA) { in = Wattn; out = WtA; R = KD; Cc = NQKV; b2 = bid - PREP_CONV; }
  else                           { in = Wproj; out = WtP; R = CC; Cc = CC;   b2 = bid - PREP_CONV - PREP_WA; }
  int ct = Cc >> 5;
  int bx = b2 % ct;
  int by = b2 / ct;
  int tx = tid & 31;
  int ty = tid >> 5;    // 0..7
  int c0 = bx << 5, r0 = by << 5;
#pragma unroll
  for (int s = 0; s < 4; ++s)
    tile[ty + s*8][tx] = in[(size_t)(r0 + ty + s*8) * Cc + c0 + tx];
  __syncthreads();
#pragma unroll
  for (int s = 0; s < 4; ++s)
    out[(size_t)(c0 + ty + s*8) * R + r0 + tx] = f2bf(tile[tx][ty + s*8]);
}

// ------- GEMM: 64x128 tile, BK=64, global_load_lds + XOR bank swizzle -------
// mode 0: q/k scattered directly; V written TRANSPOSED to vtb [bh][d][t] via
//         LDS staging; vmean partials from f32 accs. mode 1: f32 row-major out.
__global__ __launch_bounds__(256) void gemm_bt(
    const u16* __restrict__ A, const u16* __restrict__ Bt,
    const float* __restrict__ bias,
    float* __restrict__ out,
    u16* __restrict__ qo, u16* __restrict__ ko, u16* __restrict__ vo,
    float* __restrict__ mvp,
    int M, int N, int mode)
{
  __shared__ u16 smem[64 * 64 + 128 * 64];   // As | Bs ; reused as V-staging (needs 128*72)
  u16* Asm = smem;
  u16* Bsm = smem + 64 * 64;

  int tid = threadIdx.x;
  int lane = tid & 63;
  int w = tid >> 6;
  int c = lane & 15;     // fragment col
  int q4 = lane >> 4;    // quad

  int mtiles = M >> 6;
  int mt = blockIdx.x % mtiles;
  int nt = blockIdx.x / mtiles;
  int m0 = mt << 6, n0 = nt << 7;

  int wr = (w >> 1) << 5;   // 0 / 32
  int wc = (w & 1) << 6;    // 0 / 64

  int srow8 = lane >> 3;                      // 0..7
  int ug = ((lane & 7) ^ srow8) << 3;         // swizzled global k-offset (shorts)
  const u16* ag = A  + (size_t)(m0 + w * 16 + srow8) * KD + ug;
  const u16* bg = Bt + (size_t)(n0 + w * 32 + srow8) * KD + ug;
  u16* asl = &Asm[(w * 16) * 64];
  u16* bsl = &Bsm[(w * 32) * 64];

  floatx4 acc[2][4];
#pragma unroll
  for (int mi = 0; mi < 2; ++mi)
#pragma unroll
    for (int ni = 0; ni < 4; ++ni) acc[mi][ni] = (floatx4){0.f, 0.f, 0.f, 0.f};

  int c7 = c & 7;

#pragma unroll 1
  for (int kt = 0; kt < KD; kt += 64) {
    async_ld16(ag + kt,              asl);
    async_ld16(ag + kt + 8 * KD,     asl + 8 * 64);
    async_ld16(bg + kt,              bsl);
    async_ld16(bg + kt + 8 * KD,     bsl + 8 * 64);
    async_ld16(bg + kt + 16 * KD,    bsl + 16 * 64);
    async_ld16(bg + kt + 24 * KD,    bsl + 24 * 64);
    __syncthreads();

    short8v af[2][2], bf[4][2];
#pragma unroll
    for (int kc = 0; kc < 2; ++kc) {
      int uoff = ((kc * 4 + q4) ^ c7) << 3;
#pragma unroll
      for (int mi = 0; mi < 2; ++mi)
        af[mi][kc] = *(const short8v*)&Asm[(wr + mi * 16 + c) * 64 + uoff];
#pragma unroll
      for (int ni = 0; ni < 4; ++ni)
        bf[ni][kc] = *(const short8v*)&Bsm[(wc + ni * 16 + c) * 64 + uoff];
    }
#pragma unroll
    for (int kc = 0; kc < 2; ++kc)
#pragma unroll
      for (int mi = 0; mi < 2; ++mi)
#pragma unroll
        for (int ni = 0; ni < 4; ++ni)
          acc[mi][ni] = __builtin_amdgcn_mfma_f32_16x16x32_bf16(af[mi][kc], bf[ni][kc], acc[mi][ni], 0, 0, 0);
    __syncthreads();
  }

  if (mode == 0) {
    int which = (n0 + wc) / CC;          // per-wave (128-blocks can straddle q/k and k/v)
    int nbase = (n0 + wc) - which * CC;
    int bb = m0 >> 10;                   // m-range (64) never straddles a batch
    int t0 = m0 & 1023;

    if (which < 2) {
      // direct scatter: 16 c-lanes cover a contiguous 32B segment -> coalesces
      u16* dst0 = (which == 0) ? qo : ko;
#pragma unroll
      for (int ni = 0; ni < 4; ++ni) {
        int nn = nbase + ni * 16 + c;
        int hh = nn >> 6, dd = nn & 63;
        float bv = bias[which * CC + nn];
#pragma unroll
        for (int mi = 0; mi < 2; ++mi) {
#pragma unroll
          for (int r = 0; r < 4; ++r) {
            int tt2 = t0 + wr + mi * 16 + q4 * 4 + r;
            dst0[(((size_t)(bb * NH + hh)) * TT + tt2) * HD + dd] = f2bf(acc[mi][ni][r] + bv);
          }
        }
      }
    }
    // V path: block-uniform wrapper (n0 is uniform) -> barrier is legal
    if (n0 + 127 >= 2 * CC) {
      u16* Ct = smem;                    // [128 n][64 t] stride 72 (18432B <= 24576)
      if (which == 2) {
#pragma unroll
        for (int ni = 0; ni < 4; ++ni) {
          float bv = bias[2 * CC + nbase + ni * 16 + c];
#pragma unroll
          for (int mi = 0; mi < 2; ++mi) {
            short4v pk;
#pragma unroll
            for (int r = 0; r < 4; ++r) pk[r] = (short)f2bf(acc[mi][ni][r] + bv);
            *(short4v*)&Ct[(wc + ni * 16 + c) * 72 + wr + mi * 16 + q4 * 4] = pk;
          }
        }
      }
      __syncthreads();
#pragma unroll
      for (int j = 0; j < 4; ++j) {
        int flat = tid + j * 256;        // [128 rows][8 units of 16B]
        int drow = flat >> 3, u = flat & 7;
        int nn2 = n0 + drow;
        if (nn2 >= 2 * CC) {
          int nv = nn2 - 2 * CC;
          int h2 = nv >> 6, d2 = nv & 63;
          short8v val = *(const short8v*)&Ct[drow * 72 + u * 8];
          *(short8v*)&vo[(((size_t)(bb * NH + h2)) * HD + d2) * TT + t0 + u * 8] = val;
        }
      }
      // vmean partials from f32 accs (+bias): each wave sums its 32 t-rows
      if (which == 2) {
        int hw = nbase >> 6;             // wave covers exactly one head
        int bhw = bb * NH + hw;
#pragma unroll
        for (int ni = 0; ni < 4; ++ni) {
          float bv = bias[2 * CC + nbase + ni * 16 + c];
          float s = 8.0f * bv;
#pragma unroll
          for (int mi = 0; mi < 2; ++mi)
#pragma unroll
            for (int r = 0; r < 4; ++r) s += acc[mi][ni][r];
          s += __shfl_xor(s, 16);
          s += __shfl_xor(s, 32);        // sum over this wave's 32 rows
          if (q4 == 0) atomicAdd(&mvp[bhw * HD + ni * 16 + c], s);
        }
      }
    }
  } else {
#pragma unroll
    for (int ni = 0; ni < 4; ++ni) {
      int nn = n0 + wc + ni * 16 + c;
      float bv = bias[nn];
#pragma unroll
      for (int mi = 0; mi < 2; ++mi) {
#pragma unroll
        for (int r = 0; r < 4; ++r) {
          int mm = m0 + wr + mi * 16 + q4 * 4 + r;
          out[(size_t)mm * N + nn] = acc[mi][ni][r] + bv;
        }
      }
    }
  }
}

// ------- proj GEMM: 64x64 tile, BK=64, 1536 blocks -------
__global__ __launch_bounds__(256) void gemm_proj(
    const u16* __restrict__ A, const u16* __restrict__ Bt,
    const float* __restrict__ bias, float* __restrict__ out)
{
  __shared__ u16 As[64 * 64];
  __shared__ u16 Bs[64 * 64];

  int tid = threadIdx.x;
  int lane = tid & 63;
  int w = tid >> 6;
  int c = lane & 15;
  int q4 = lane >> 4;

  int mt = blockIdx.x & 127;      // 128 mtiles
  int nt = blockIdx.x >> 7;       // 12 ntiles
  int m0 = mt << 6, n0 = nt << 6;

  int wr = (w >> 1) << 5;   // 0 / 32
  int wc = (w & 1) << 5;    // 0 / 32

  int srow8 = lane >> 3;
  int ug = ((lane & 7) ^ srow8) << 3;
  const u16* ag = A  + (size_t)(m0 + w * 16 + srow8) * KD + ug;
  const u16* bg = Bt + (size_t)(n0 + w * 16 + srow8) * KD + ug;
  u16* asl = &As[(w * 16) * 64];
  u16* bsl = &Bs[(w * 16) * 64];

  floatx4 acc[2][2];
#pragma unroll
  for (int mi = 0; mi < 2; ++mi)
#pragma unroll
    for (int ni = 0; ni < 2; ++ni) acc[mi][ni] = (floatx4){0.f, 0.f, 0.f, 0.f};

  int c7 = c & 7;

#pragma unroll 1
  for (int kt = 0; kt < KD; kt += 64) {
    async_ld16(ag + kt,          asl);
    async_ld16(ag + kt + 8 * KD, asl + 8 * 64);
    async_ld16(bg + kt,          bsl);
    async_ld16(bg + kt + 8 * KD, bsl + 8 * 64);
    __syncthreads();

    short8v af[2][2], bf[2][2];
#pragma unroll
    for (int kc = 0; kc < 2; ++kc) {
      int uoff = ((kc * 4 + q4) ^ c7) << 3;
#pragma unroll
      for (int mi = 0; mi < 2; ++mi)
        af[mi][kc] = *(const short8v*)&As[(wr + mi * 16 + c) * 64 + uoff];
#pragma unroll
      for (int ni = 0; ni < 2; ++ni)
        bf[ni][kc] = *(const short8v*)&Bs[(wc + ni * 16 + c) * 64 + uoff];
    }
#pragma unroll
    for (int kc = 0; kc < 2; ++kc)
#pragma unroll
      for (int mi = 0; mi < 2; ++mi)
#pragma unroll
        for (int ni = 0; ni < 2; ++ni)
          acc[mi][ni] = __builtin_amdgcn_mfma_f32_16x16x32_bf16(af[mi][kc], bf[ni][kc], acc[mi][ni], 0, 0, 0);
    __syncthreads();
  }

#pragma unroll
  for (int ni = 0; ni < 2; ++ni) {
    int nn = n0 + wc + ni * 16 + c;
    float bv = bias[nn];
#pragma unroll
    for (int mi = 0; mi < 2; ++mi) {
#pragma unroll
      for (int r = 0; r < 4; ++r) {
        int mm = m0 + wr + mi * 16 + q4 * 4 + r;
        out[(size_t)mm * CC + nn] = acc[mi][ni][r] + bv;
      }
    }
  }
}

// ---------------- MFMA flash attention: MERGED dual-q-tile k-loop ----------------
// Each block handles q-tiles qtA=pair (0..7) and qtB=15-pair (8..15) in ONE
// k-loop kt=0..qtB: tile A active only while kt<=qtA. Shared kf LDS reads feed
// both tiles' QK MFMAs. LDS staging is the coalescing mechanism (R11: L2-direct
// fragment reads are 16-way scattered gathers -> 2x regression). XCD swizzle
// keeps one bh's blocks on one XCD L2.
#define LDW 72
#define SCL 0.18033688f   // (1/sqrt(64)) * log2(e); softmax in exp2 domain

__global__ __launch_bounds__(256, 3) void attn_kernel(
    const u16* __restrict__ qb, const u16* __restrict__ kb,
    const u16* __restrict__ vtb, const int* __restrict__ mask,
    const float* __restrict__ meanv,
    u16* __restrict__ outb)
{
  __shared__ u16 Ks[2][64 * LDW];    // K tile [key][d], double-buffered
  __shared__ u16 Vs[2][64 * LDW];    // V^T tile [d][key], double-buffered
  __shared__ u16 Ps[4][16 * LDW];    // per-wave P [row][key] (shared A/B, sequential)

  int tid = threadIdx.x;
  int lane = tid & 63;
  int w = tid >> 6;
  int c = lane & 15;
  int q4 = lane >> 4;

  // XCD-aware bijective swizzle: nwg=768, 768%8==0 -> lbid = (hw&7)*96 + hw/8
  int lbid = ((blockIdx.x & 7) * 96) + (blockIdx.x >> 3);
  int pair = lbid & 7;
  int bh = lbid >> 3;
  int b = bh / NH;
  int h = bh - b * NH;

  int qtA = pair;          // 0..7
  int qtB = 15 - pair;     // 8..15  (qtA < qtB always)
  int rowbaseA = (qtA << 6) + (w << 4);
  int rowbaseB = (qtB << 6) + (w << 4);

  int srow = tid >> 2;
  int schunk = (tid & 3) << 4;
  const u16* kgp = kb + ((size_t)bh * TT + srow) * HD + schunk;
  const u16* vgp = vtb + ((size_t)bh * HD + srow) * TT + schunk;
  u16* pw = &Ps[w][0];

  short8v onesv;
#pragma unroll
  for (int j = 0; j < 8; ++j) onesv[j] = (short)0x3F80;   // bf16 1.0

  short8v qfA[2], qfB[2];
  {
    const u16* qpA = qb + ((size_t)bh * TT + rowbaseA + c) * HD + q4 * 8;
    qfA[0] = *(const short8v*)qpA;
    qfA[1] = *(const short8v*)(qpA + 32);
    const u16* qpB = qb + ((size_t)bh * TT + rowbaseB + c) * HD + q4 * 8;
    qfB[0] = *(const short8v*)qpB;
    qfB[1] = *(const short8v*)(qpB + 32);
  }

  floatx4 oA[4], oB[4];
#pragma unroll
  for (int i = 0; i < 4; ++i) {
    oA[i] = (floatx4){0.f, 0.f, 0.f, 0.f};
    oB[i] = (floatx4){0.f, 0.f, 0.f, 0.f};
  }
  floatx4 o5A = (floatx4){0.f, 0.f, 0.f, 0.f};
  floatx4 o5B = (floatx4){0.f, 0.f, 0.f, 0.f};

  // prologue: tile 0 into buffer 0
  short8v kr0 = *(const short8v*)kgp;
  short8v kr1 = *(const short8v*)(kgp + 8);
  short8v vr0 = *(const short8v*)vgp;
  short8v vr1 = *(const short8v*)(vgp + 8);
  {
    u16* kd = &Ks[0][srow * LDW + schunk];
    u16* vd = &Vs[0][srow * LDW + schunk];
    *(short8v*)kd = kr0; *(short8v*)(kd + 8) = kr1;
    *(short8v*)vd = vr0; *(short8v*)(vd + 8) = vr1;
  }

  int qrl = (w << 4) + c;   // local q-row within 64-tile

#pragma unroll 1
  for (int kt = 0; kt <= qtB; ++kt) {
    int cur = kt & 1;
    __syncthreads();               // buf[cur] staged; prior reads of buf[cur^1] done

    if (kt < qtB) {                // issue next-tile loads early
      const u16* kp = kgp + ((size_t)(kt + 1) << 6) * HD;
      const u16* vp = vgp + ((kt + 1) << 6);
      kr0 = *(const short8v*)kp;
      kr1 = *(const short8v*)(kp + 8);
      vr0 = *(const short8v*)vp;
      vr1 = *(const short8v*)(vp + 8);
    }

    bool doA = (kt <= qtA);

    // QK for both tiles, SHARED kf reads. S^T: s[nt] = S[key=nt*16+q4*4+r][qrow=c]
    floatx4 sA[4], sB[4];
#pragma unroll
    for (int nt = 0; nt < 4; ++nt) {
      sA[nt] = (floatx4){0.f, 0.f, 0.f, 0.f};
      sB[nt] = (floatx4){0.f, 0.f, 0.f, 0.f};
    }
    __builtin_amdgcn_s_setprio(1);
#pragma unroll
    for (int kc = 0; kc < 2; ++kc) {
#pragma unroll
      for (int nt = 0; nt < 4; ++nt) {
        short8v kf = *(const short8v*)&Ks[cur][(nt * 16 + c) * LDW + kc * 32 + q4 * 8];
        if (doA) sA[nt] = __builtin_amdgcn_mfma_f32_16x16x32_bf16(kf, qfA[kc], sA[nt], 0, 0, 0);
        sB[nt] = __builtin_amdgcn_mfma_f32_16x16x32_bf16(kf, qfB[kc], sB[nt], 0, 0, 0);
      }
    }
    __builtin_amdgcn_s_setprio(0);

    // ---- tile A: softmax -> Ps -> PV ----
    if (doA) {
#pragma unroll
      for (int nt = 0; nt < 4; ++nt) {
        short4v pk;
#pragma unroll
        for (int r = 0; r < 4; ++r) {
          float sv = sA[nt][r];
          if (kt == qtA && (nt * 16 + (q4 << 2) + r > qrl)) sv = -INFINITY;
          pk[r] = (short)f2bf(fast_exp2(sv * SCL));
        }
        *(short4v*)&pw[c * LDW + nt * 16 + (q4 << 2)] = pk;
      }
      __builtin_amdgcn_s_setprio(1);
#pragma unroll
      for (int kc = 0; kc < 2; ++kc) {
        short8v pf = *(const short8v*)&pw[c * LDW + kc * 32 + q4 * 8];
#pragma unroll
        for (int nt = 0; nt < 4; ++nt) {
          short8v vf = *(const short8v*)&Vs[cur][(nt * 16 + c) * LDW + kc * 32 + q4 * 8];
          oA[nt] = __builtin_amdgcn_mfma_f32_16x16x32_bf16(pf, vf, oA[nt], 0, 0, 0);
        }
        o5A = __builtin_amdgcn_mfma_f32_16x16x32_bf16(pf, onesv, o5A, 0, 0, 0);
      }
      __builtin_amdgcn_s_setprio(0);
    }

    // ---- tile B: softmax -> Ps (reuse; same-wave WAR ordering) ----
#pragma unroll
    for (int nt = 0; nt < 4; ++nt) {
      short4v pk;
#pragma unroll
      for (int r = 0; r < 4; ++r) {
        float sv = sB[nt][r];
        if (kt == qtB && (nt * 16 + (q4 << 2) + r > qrl)) sv = -INFINITY;
        pk[r] = (short)f2bf(fast_exp2(sv * SCL));
      }
      *(short4v*)&pw[c * LDW + nt * 16 + (q4 << 2)] = pk;
    }

    if (kt < qtB) {                // write next tile while this one is consumed
      u16* kd = &Ks[cur ^ 1][srow * LDW + schunk];
      u16* vd = &Vs[cur ^ 1][srow * LDW + schunk];
      *(short8v*)kd = kr0; *(short8v*)(kd + 8) = kr1;
      *(short8v*)vd = vr0; *(short8v*)(vd + 8) = vr1;
    }

    // ---- tile B: PV ----
    __builtin_amdgcn_s_setprio(1);
#pragma unroll
    for (int kc = 0; kc < 2; ++kc) {
      short8v pf = *(const short8v*)&pw[c * LDW + kc * 32 + q4 * 8];
#pragma unroll
      for (int nt = 0; nt < 4; ++nt) {
        short8v vf = *(const short8v*)&Vs[cur][(nt * 16 + c) * LDW + kc * 32 + q4 * 8];
        oB[nt] = __builtin_amdgcn_mfma_f32_16x16x32_bf16(pf, vf, oB[nt], 0, 0, 0);
      }
      o5B = __builtin_amdgcn_mfma_f32_16x16x32_bf16(pf, onesv, o5B, 0, 0, 0);
    }
    __builtin_amdgcn_s_setprio(0);
  }

  // ---- epilogue: both tiles ----
#pragma unroll
  for (int t = 0; t < 2; ++t) {
    int rowbase = t ? rowbaseB : rowbaseA;
    floatx4* o = t ? oB : oA;
    floatx4 o5 = t ? o5B : o5A;
    int qrow[4]; bool msk[4]; float inv[4];
#pragma unroll
    for (int r = 0; r < 4; ++r) {
      qrow[r] = rowbase + q4 * 4 + r;
      msk[r] = (mask[b * TT + qrow[r]] == 0);
      inv[r] = 1.f / o5[r];
    }
#pragma unroll
    for (int nt = 0; nt < 4; ++nt) {
      int d = nt * 16 + c;
      float mv = meanv[bh * HD + d] * 0.0009765625f;   // raw sum -> mean (1/1024)
#pragma unroll
      for (int r = 0; r < 4; ++r) {
        float val = msk[r] ? mv : o[nt][r] * inv[r];
        outb[((size_t)(b * TT + qrow[r])) * CC + h * HD + d] = f2bf(val);
      }
    }
  }
}

// ---------------- launcher ----------------
extern "C" void kernel_launch(void* const* d_in, const int* in_sizes, int n_in,
                              void* d_out, int out_size, void* d_ws, size_t ws_size,
                              hipStream_t stream)
{
  (void)in_sizes; (void)n_in; (void)out_size; (void)ws_size;
  const float* x     = (const float*)d_in[0];
  const int*   mask  = (const int*)d_in[1];
  const float* Wattn = (const float*)d_in[2];
  const float* battn = (const float*)d_in[3];
  const float* Wproj = (const float*)d_in[4];
  const float* bproj = (const float*)d_in[5];
  float* out = (float*)d_out;

  char* ws = (char*)d_ws;
  size_t off = 0;
  auto alloc = [&](size_t bytes) -> void* {
    void* p = ws + off;
    off += (bytes + 255) & ~(size_t)255;
    return p;
  };
  u16* WtA  = (u16*)alloc((size_t)NQKV * KD * 2);
  u16* WtP  = (u16*)alloc((size_t)CC * CC * 2);
  u16* xb   = (u16*)alloc((size_t)MROWS * CC * 2);
  u16* qbuf = (u16*)alloc((size_t)MROWS * CC * 2);
  u16* kbuf = (u16*)alloc((size_t)MROWS * CC * 2);
  u16* vtb  = (u16*)alloc((size_t)MROWS * CC * 2);   // V^T [bh][d][t] (written by gemm0)
  u16* abuf = (u16*)alloc((size_t)MROWS * CC * 2);
  float* mv = (float*)alloc((size_t)BH * HD * 4);

  prep_kernel<<<PREP_TOTAL + 1, 256, 0, stream>>>(x, xb, Wattn, WtA, Wproj, WtP, mv);

  gemm_bt<<<(MROWS/64)*(NQKV/128), 256, 0, stream>>>(
      xb, WtA, battn, nullptr, qbuf, kbuf, vtb, mv, MROWS, NQKV, 0);

  attn_kernel<<<BH * 8, 256, 0, stream>>>(qbuf, kbuf, vtb, mask, mv, abuf);

  gemm_proj<<<(MROWS/64)*(CC/64), 256, 0, stream>>>(abuf, WtP, bproj, out);
}